// Round 2
// baseline (402.623 us; speedup 1.0000x reference)
//
#include <hip/hip_runtime.h>
#include <math.h>

#define B_N 2048
#define L_N 64
#define D_N 256   // EMBED_DIM
#define U_N 512   // UNITS
#define NB  4     // batches per attn block (cross-b pipeline depth)

typedef __attribute__((ext_vector_type(8))) short bf16x8;   // 8 bf16 = 4 VGPRs
typedef __attribute__((ext_vector_type(4))) float f32x4;    // MFMA 16x16 acc

// tanh(x) = 1 - 2/(2^(x*2*log2e)+1)
__device__ __forceinline__ float fast_tanh(float x) {
    float e = __builtin_amdgcn_exp2f(x * 2.8853900817779268f);
    float r = __builtin_amdgcn_rcpf(e + 1.0f);
    return fmaf(-2.0f, r, 1.0f);
}
// fp32 -> bf16 round-to-nearest-even
__device__ __forceinline__ ushort f2bf(float x) {
    uint b = __float_as_uint(x);
    uint r = (b + 0x7FFF + ((b >> 16) & 1)) >> 16;
    return (ushort)r;
}
__device__ __forceinline__ float bf2f(ushort u) {
    uint v = ((uint)u) << 16;
    return __uint_as_float(v);
}

// async global->LDS 16B: zero VGPR payload, counted in vmcnt.
// LDS dest is wave-uniform base + lane*16 (HW adds lane offset).
__device__ __forceinline__ void gll16(const ushort* g, ushort* l) {
    __builtin_amdgcn_global_load_lds(
        (const __attribute__((address_space(1))) unsigned int*)g,
        (__attribute__((address_space(3))) unsigned int*)l,
        16, 0, 0);
}

// ---------------------------------------------------------------------------
// K0 prep: pack W1/W2 -> bf16 MFMA B-fragment order (as before), AND convert
// features fp32 -> bf16 row-major (64 MB) so attn can stage via global_load_lds.
// Streaming, fully coalesced; 2240 blocks.
// ---------------------------------------------------------------------------
__global__ __launch_bounds__(256) void prep(
    const float* __restrict__ W1, const float* __restrict__ W2,
    const float* __restrict__ features,
    ushort* __restrict__ W1p, ushort* __restrict__ W2p, ushort* __restrict__ fbf)
{
    const int t = threadIdx.x;
    if (blockIdx.x < 64) {
        ushort tmp[8];
        int g = blockIdx.x * 256 + t;                // 0..16383
        int ntg = g >> 9, ks = (g >> 6) & 7, lane = g & 63;
        int n  = ntg * 16 + (lane & 15);
        int kb = ks * 32 + (lane >> 4) * 8;
#pragma unroll
        for (int j = 0; j < 8; ++j) tmp[j] = f2bf(W1[(kb + j) * U_N + n]);
        *(uint4*)&W1p[(size_t)g * 8] = *(uint4*)tmp;
    } else if (blockIdx.x < 192) {
        ushort tmp[8];
        int g = (blockIdx.x - 64) * 256 + t;         // 0..32767
        int ntg = g >> 10, ks = (g >> 6) & 15, lane = g & 63;
        int n  = ntg * 16 + (lane & 15);
        int kb = ks * 32 + (lane >> 4) * 8;
#pragma unroll
        for (int j = 0; j < 8; ++j) tmp[j] = f2bf(W2[(kb + j) * U_N + n]);
        *(uint4*)&W2p[(size_t)g * 8] = *(uint4*)tmp;
    } else {
        int b = blockIdx.x - 192;                    // 0..2047
        const float* fb = features + (size_t)b * (L_N * D_N);
        ushort* fo = fbf + (size_t)b * (L_N * D_N);
#pragma unroll
        for (int i = 0; i < 8; ++i) {
            int ch = t + i * 256;                    // chunk of 8 elems
            float4 x0 = *(const float4*)&fb[ch * 8];
            float4 x1 = *(const float4*)&fb[ch * 8 + 4];
            ushort tv[8] = {f2bf(x0.x), f2bf(x0.y), f2bf(x0.z), f2bf(x0.w),
                            f2bf(x1.x), f2bf(x1.y), f2bf(x1.z), f2bf(x1.w)};
            *(uint4*)&fo[(size_t)ch * 8] = *(uint4*)tv;
        }
    }
}

// ---------------------------------------------------------------------------
// K1: ph = hidden @ W2 + b1 + b2 via bf16 MFMA, stored bf16. (unchanged)
// ---------------------------------------------------------------------------
__global__ __launch_bounds__(256) void proj_h_mfma(
    const float* __restrict__ hidden, const ushort* __restrict__ W2p,
    const float* __restrict__ b1, const float* __restrict__ b2,
    ushort* __restrict__ ph)
{
    __shared__ ushort As[16 * 512];   // 16 KB

    const int t  = threadIdx.x;
    const int b0 = blockIdx.x * 16;
    const int u0 = blockIdx.y * 128;

#pragma unroll
    for (int i = 0; i < 4; ++i) {
        int f = t + i * 256;
        int m = f >> 6, c = f & 63;
        float4 x0 = *(const float4*)&hidden[(b0 + m) * U_N + c * 8];
        float4 x1 = *(const float4*)&hidden[(b0 + m) * U_N + c * 8 + 4];
        ushort tmp[8] = {f2bf(x0.x), f2bf(x0.y), f2bf(x0.z), f2bf(x0.w),
                         f2bf(x1.x), f2bf(x1.y), f2bf(x1.z), f2bf(x1.w)};
        *(uint4*)&As[(m * 64 + (c ^ (m & 7))) * 8] = *(uint4*)tmp;
    }
    __syncthreads();

    const int w = t >> 6, lane = t & 63;
    const int ml = lane & 15, q = lane >> 4;

    f32x4 acc[2];
#pragma unroll
    for (int nt = 0; nt < 2; ++nt) acc[nt] = (f32x4){0.f, 0.f, 0.f, 0.f};

    for (int ks = 0; ks < 16; ++ks) {
        int c = ks * 4 + q;
        bf16x8 a = *(const bf16x8*)&As[(ml * 64 + (c ^ (ml & 7))) * 8];
        bf16x8 bb[2];
#pragma unroll
        for (int nt = 0; nt < 2; ++nt) {
            int ntg = blockIdx.y * 8 + w * 2 + nt;
            bb[nt] = *(const bf16x8*)&W2p[(size_t)((ntg * 16 + ks) * 64 + lane) * 8];
        }
#pragma unroll
        for (int nt = 0; nt < 2; ++nt)
            acc[nt] = __builtin_amdgcn_mfma_f32_16x16x32_bf16(a, bb[nt], acc[nt], 0, 0, 0);
    }

#pragma unroll
    for (int nt = 0; nt < 2; ++nt) {
        int n = u0 + (w * 2 + nt) * 16 + ml;
        float bias = b1[n] + b2[n];
#pragma unroll
        for (int r = 0; r < 4; ++r)
            ph[(size_t)(b0 + q * 4 + r) * U_N + n] = f2bf(acc[nt][r] + bias);
    }
}

// ---------------------------------------------------------------------------
// K2: per-batch fused attention, bf16 MFMA.
// Cross-b pipeline via global_load_lds (zero VGPR payload): double-buffered
// 32 KB bf16 tiles; loads for b+1 issued at top of b's compute, drained by
// vmcnt(0)+barrier at iteration end. LDS swizzle preserved by inverse-swizzled
// per-lane GLOBAL source (linear LDS dest = uniform base + lane*16).
// uc widened 4->2 (acc[4][4]=64 VGPR): a-frag ds_read_b128 128->64/wave,
// halving the dominant LDS-pipe term. LDS 66 KB -> 2 blocks/CU = 2 waves/SIMD,
// so waves_per_eu(2,2) pins the full 256-VGPR budget (R1 spilled at a
// heuristic 128 despite launch_bounds).
// ---------------------------------------------------------------------------
__global__ __launch_bounds__(256)
__attribute__((amdgpu_waves_per_eu(2, 2)))
void attn_kernel(
    const ushort* __restrict__ fbf, const ushort* __restrict__ W1p,
    const float* __restrict__ V, const float* __restrict__ bV,
    const ushort* __restrict__ ph, float* __restrict__ out)
{
    __shared__ ushort As[2][64 * 256];   // 2 x 32 KB, chunk (m,c) at m*32 + (c^(m&31))
    __shared__ float lpart[4][64];
    __shared__ float wls[64];

    const int t    = threadIdx.x;
    const int w    = t >> 6;
    const int lane = t & 63;
    const int ml   = lane & 15;
    const int q    = lane >> 4;
    const int b0   = blockIdx.x * NB;

    // issue one 64x256 bf16 tile (32 KB) async: 8 instrs/wave, 1 KB each.
    // LDS pos p = m*32+cc receives global chunk m*32 + (cc ^ (m&31)).
#define ISSUE(bb, buf) do {                                                   \
        const ushort* fb_ = fbf + (size_t)(bb) * (L_N * D_N);                 \
        _Pragma("unroll")                                                     \
        for (int i = 0; i < 8; ++i) {                                         \
            int p0_ = w * 512 + i * 64;          /* wave-uniform */           \
            int p_  = p0_ + lane;                                             \
            int m_  = p_ >> 5, cc_ = p_ & 31;                                 \
            int s_  = m_ * 32 + (cc_ ^ (m_ & 31));                            \
            gll16(fb_ + (size_t)s_ * 8, &As[buf][p0_ * 8]);                   \
        }                                                                     \
    } while (0)

    // prologue: stage b0 into buffer 0
    ISSUE(b0, 0);
    asm volatile("s_waitcnt vmcnt(0)" ::: "memory");
    __syncthreads();

    const ushort* W1w = W1p + (size_t)(w * 8) * 8 * 64 * 8;  // wave's 128-u strip
    int cur = 0;

    for (int bi = 0; bi < NB; ++bi) {
        const int b = b0 + bi;

        // async-issue next tile into the free buffer; drains under this
        // iteration's MFMA + epilogue (~5k cyc >> L3/HBM latency)
        if (bi + 1 < NB) ISSUE(b + 1, cur ^ 1);

        float lp[16];
#pragma unroll
        for (int j = 0; j < 16; ++j) lp[j] = 0.f;

#pragma unroll
        for (int uc = 0; uc < 2; ++uc) {
            f32x4 acc[4][4];   // [mt][nt] : 64 rows x 64 cols per uc
#pragma unroll
            for (int mt = 0; mt < 4; ++mt)
#pragma unroll
                for (int nt = 0; nt < 4; ++nt)
                    acc[mt][nt] = (f32x4){0.f, 0.f, 0.f, 0.f};

            bf16x8 bfc[4], bfn[4];
#pragma unroll
            for (int nt = 0; nt < 4; ++nt)
                bfc[nt] = *(const bf16x8*)&W1w[(size_t)(((uc * 4 + nt) * 8 + 0) * 64 + lane) * 8];

            for (int ks = 0; ks < 8; ++ks) {
                if (ks < 7) {
#pragma unroll
                    for (int nt = 0; nt < 4; ++nt)
                        bfn[nt] = *(const bf16x8*)&W1w[(size_t)(((uc * 4 + nt) * 8 + ks + 1) * 64 + lane) * 8];
                }
                bf16x8 a[4];
#pragma unroll
                for (int mt = 0; mt < 4; ++mt) {
                    int m = mt * 16 + ml;
                    int c = ks * 4 + q;
                    a[mt] = *(const bf16x8*)&As[cur][(m * 32 + (c ^ (m & 31))) * 8];
                }
#pragma unroll
                for (int nt = 0; nt < 4; ++nt)
#pragma unroll
                    for (int mt = 0; mt < 4; ++mt)
                        acc[mt][nt] = __builtin_amdgcn_mfma_f32_16x16x32_bf16(
                            a[mt], bfc[nt], acc[mt][nt], 0, 0, 0);
#pragma unroll
                for (int nt = 0; nt < 4; ++nt) bfc[nt] = bfn[nt];
            }

            // fold 64-u chunk into persistent lp.  D: n=nt*16+ml, m=mt*16+q*4+r
#pragma unroll
            for (int nt = 0; nt < 4; ++nt) {
                int n = w * 128 + uc * 64 + nt * 16 + ml;
                float phv = bf2f(ph[(size_t)b * U_N + n]);
                float vv  = V[n];
#pragma unroll
                for (int mt = 0; mt < 4; ++mt)
#pragma unroll
                    for (int r = 0; r < 4; ++r) {
                        float s = fast_tanh(acc[mt][nt][r] + phv);
                        lp[mt * 4 + r] = fmaf(s, vv, lp[mt * 4 + r]);
                    }
            }
        }

        // shuffle-reduce over the 16 n-lanes (xor 1,2,4,8 stays within q-group)
#pragma unroll
        for (int off = 1; off <= 8; off <<= 1)
#pragma unroll
            for (int j = 0; j < 16; ++j)
                lp[j] += __shfl_xor(lp[j], off);

        if (ml == 0) {
#pragma unroll
            for (int mt = 0; mt < 4; ++mt)
#pragma unroll
                for (int r = 0; r < 4; ++r)
                    lpart[w][mt * 16 + q * 4 + r] = lp[mt * 4 + r];
        }
        __syncthreads();   // BARRIER B: lpart ready

        if (t < 64) {
            float lsum = bV[0] + lpart[0][t] + lpart[1][t] + lpart[2][t] + lpart[3][t];
            float mx = lsum;
#pragma unroll
            for (int off = 32; off > 0; off >>= 1)
                mx = fmaxf(mx, __shfl_xor(mx, off));
            float e = __expf(lsum - mx);
            float ssum = e;
#pragma unroll
            for (int off = 32; off > 0; off >>= 1)
                ssum += __shfl_xor(ssum, off);
            float wt = e / ssum;
            wls[t] = wt;
            out[(size_t)B_N * D_N + (size_t)b * L_N + t] = wt;
        }
        __syncthreads();   // BARRIER C: wls ready

        // context[d] = sum_l w_l * f[l][d], from LDS bf16 (t == d)
        float ctx = 0.f;
#pragma unroll 16
        for (int l = 0; l < L_N; ++l) {
            ushort u = As[cur][(l * 32 + ((t >> 3) ^ (l & 31))) * 8 + (t & 7)];
            ctx = fmaf(wls[l], bf2f(u), ctx);
        }
        out[(size_t)b * D_N + t] = ctx;

        // boundary: drain our async loads (targets As[cur^1]) + make visible
        // to all waves; also closes ctx reads of As[cur] before next overwrite.
        asm volatile("s_waitcnt vmcnt(0)" ::: "memory");
        __syncthreads();
        cur ^= 1;
    }
#undef ISSUE
}

// ---------------------------------------------------------------------------
extern "C" void kernel_launch(void* const* d_in, const int* in_sizes, int n_in,
                              void* d_out, int out_size, void* d_ws, size_t ws_size,
                              hipStream_t stream) {
    const float* features = (const float*)d_in[0];
    const float* hidden   = (const float*)d_in[1];
    const float* W1       = (const float*)d_in[2];
    const float* b1       = (const float*)d_in[3];
    const float* W2       = (const float*)d_in[4];
    const float* b2       = (const float*)d_in[5];
    const float* V        = (const float*)d_in[6];
    const float* bV       = (const float*)d_in[7];
    float* out = (float*)d_out;

    // ws: ph bf16 2 MB @0 | W1p 256 KB | W2p 512 KB | fbf bf16 64 MB
    ushort* ph  = (ushort*)d_ws;
    ushort* W1p = (ushort*)((char*)d_ws + (size_t)B_N * U_N * 2);
    ushort* W2p = (ushort*)((char*)d_ws + (size_t)B_N * U_N * 2 + (size_t)D_N * U_N * 2);
    ushort* fbf = (ushort*)((char*)d_ws + (size_t)B_N * U_N * 2 + (size_t)D_N * U_N * 2
                                        + (size_t)U_N * U_N * 2);

    prep<<<192 + B_N, 256, 0, stream>>>(W1, W2, features, W1p, W2p, fbf);
    proj_h_mfma<<<dim3(B_N / 16, U_N / 128), 256, 0, stream>>>(hidden, W2p, b1, b2, ph);
    attn_kernel<<<B_N / NB, 256, 0, stream>>>(fbf, W1p, V, bV, ph, out);
}

// Round 3
// 303.146 us; speedup vs baseline: 1.3281x; 1.3281x over previous
//
#include <hip/hip_runtime.h>
#include <math.h>

#define B_N 2048
#define L_N 64
#define D_N 256   // EMBED_DIM
#define U_N 512   // UNITS
#define NB  4     // batches per attn block (cross-b pipeline depth)

typedef __attribute__((ext_vector_type(8))) short bf16x8;   // 8 bf16 = 4 VGPRs
typedef __attribute__((ext_vector_type(4))) float f32x4;    // MFMA 16x16 acc

// tanh(x) = 1 - 2/(2^(x*2*log2e)+1)
__device__ __forceinline__ float fast_tanh(float x) {
    float e = __builtin_amdgcn_exp2f(x * 2.8853900817779268f);
    float r = __builtin_amdgcn_rcpf(e + 1.0f);
    return fmaf(-2.0f, r, 1.0f);
}
// fp32 -> bf16 round-to-nearest-even
__device__ __forceinline__ ushort f2bf(float x) {
    uint b = __float_as_uint(x);
    uint r = (b + 0x7FFF + ((b >> 16) & 1)) >> 16;
    return (ushort)r;
}
__device__ __forceinline__ float bf2f(ushort u) {
    uint v = ((uint)u) << 16;
    return __uint_as_float(v);
}

// async global->LDS 16B: zero VGPR payload, counted in vmcnt.
// LDS dest = wave-uniform base; HW adds lane*16.
__device__ __forceinline__ void gll16(const ushort* g, ushort* l) {
    __builtin_amdgcn_global_load_lds(
        (const __attribute__((address_space(1))) unsigned int*)g,
        (__attribute__((address_space(3))) unsigned int*)l,
        16, 0, 0);
}

// ---------------------------------------------------------------------------
// K0: pack W1 [256,512] and W2 [512,512] fp32 -> bf16 MFMA B-fragment order.
// chunk g = (ntg*KS + ks)*64 + lane holds W[ks*32 + (lane>>4)*8 + j][ntg*16 + (lane&15)]
// ---------------------------------------------------------------------------
__global__ __launch_bounds__(256) void pack_weights(
    const float* __restrict__ W1, const float* __restrict__ W2,
    ushort* __restrict__ W1p, ushort* __restrict__ W2p)
{
    ushort tmp[8];
    if (blockIdx.x < 64) {
        int g = blockIdx.x * 256 + threadIdx.x;      // 0..16383
        int ntg = g >> 9, ks = (g >> 6) & 7, lane = g & 63;
        int n  = ntg * 16 + (lane & 15);
        int kb = ks * 32 + (lane >> 4) * 8;
#pragma unroll
        for (int j = 0; j < 8; ++j) tmp[j] = f2bf(W1[(kb + j) * U_N + n]);
        *(uint4*)&W1p[(size_t)g * 8] = *(uint4*)tmp;
    } else {
        int g = (blockIdx.x - 64) * 256 + threadIdx.x;  // 0..32767
        int ntg = g >> 10, ks = (g >> 6) & 15, lane = g & 63;
        int n  = ntg * 16 + (lane & 15);
        int kb = ks * 32 + (lane >> 4) * 8;
#pragma unroll
        for (int j = 0; j < 8; ++j) tmp[j] = f2bf(W2[(kb + j) * U_N + n]);
        *(uint4*)&W2p[(size_t)g * 8] = *(uint4*)tmp;
    }
}

// ---------------------------------------------------------------------------
// K1: fused  (a) ph = hidden @ W2 + b1 + b2 via bf16 MFMA   [blocks 0..511]
//            (b) features fp32 -> bf16 row-major (fbf)       [blocks 512..2559]
// Conversion stream (192 MB) overlaps proj's MFMA compute instead of being a
// separate serial dispatch. fbf enables global_load_lds staging in attn.
// ---------------------------------------------------------------------------
__global__ __launch_bounds__(256) void proj_conv(
    const float* __restrict__ hidden, const ushort* __restrict__ W2p,
    const float* __restrict__ b1, const float* __restrict__ b2,
    const float* __restrict__ features,
    ushort* __restrict__ ph, ushort* __restrict__ fbf)
{
    const int t  = threadIdx.x;
    const int bx = blockIdx.x;

    if (bx >= 512) {                       // ---- feature conversion ----
        int b = bx - 512;                  // 0..2047
        const float* fb = features + (size_t)b * (L_N * D_N);
        ushort* fo = fbf + (size_t)b * (L_N * D_N);
#pragma unroll
        for (int i = 0; i < 8; ++i) {
            int ch = t + i * 256;          // chunk of 8 elems
            float4 x0 = *(const float4*)&fb[ch * 8];
            float4 x1 = *(const float4*)&fb[ch * 8 + 4];
            ushort tv[8] = {f2bf(x0.x), f2bf(x0.y), f2bf(x0.z), f2bf(x0.w),
                            f2bf(x1.x), f2bf(x1.y), f2bf(x1.z), f2bf(x1.w)};
            *(uint4*)&fo[(size_t)ch * 8] = *(uint4*)tv;
        }
        return;
    }

    // ---- proj: b0 strip x 128-u strip ----
    __shared__ ushort As[16 * 512];   // 16 KB
    const int b0 = (bx & 127) * 16;
    const int ug = bx >> 7;           // 0..3
    const int u0 = ug * 128;

#pragma unroll
    for (int i = 0; i < 4; ++i) {
        int f = t + i * 256;
        int m = f >> 6, c = f & 63;
        float4 x0 = *(const float4*)&hidden[(b0 + m) * U_N + c * 8];
        float4 x1 = *(const float4*)&hidden[(b0 + m) * U_N + c * 8 + 4];
        ushort tmp[8] = {f2bf(x0.x), f2bf(x0.y), f2bf(x0.z), f2bf(x0.w),
                         f2bf(x1.x), f2bf(x1.y), f2bf(x1.z), f2bf(x1.w)};
        *(uint4*)&As[(m * 64 + (c ^ (m & 7))) * 8] = *(uint4*)tmp;
    }
    __syncthreads();

    const int w = t >> 6, lane = t & 63;
    const int ml = lane & 15, q = lane >> 4;

    f32x4 acc[2];
#pragma unroll
    for (int nt = 0; nt < 2; ++nt) acc[nt] = (f32x4){0.f, 0.f, 0.f, 0.f};

    for (int ks = 0; ks < 16; ++ks) {
        int c = ks * 4 + q;
        bf16x8 a = *(const bf16x8*)&As[(ml * 64 + (c ^ (ml & 7))) * 8];
        bf16x8 bb[2];
#pragma unroll
        for (int nt = 0; nt < 2; ++nt) {
            int ntg = ug * 8 + w * 2 + nt;
            bb[nt] = *(const bf16x8*)&W2p[(size_t)((ntg * 16 + ks) * 64 + lane) * 8];
        }
#pragma unroll
        for (int nt = 0; nt < 2; ++nt)
            acc[nt] = __builtin_amdgcn_mfma_f32_16x16x32_bf16(a, bb[nt], acc[nt], 0, 0, 0);
    }

#pragma unroll
    for (int nt = 0; nt < 2; ++nt) {
        int n = u0 + (w * 2 + nt) * 16 + ml;
        float bias = b1[n] + b2[n];
#pragma unroll
        for (int r = 0; r < 4; ++r)
            ph[(size_t)(b0 + q * 4 + r) * U_N + n] = f2bf(acc[nt][r] + bias);
    }
}

// ---------------------------------------------------------------------------
// K2: per-batch fused attention, bf16 MFMA.
// R0's PROVEN compute structure (uc=4, acc[4][2], 1-deep B-dbuf -> 120 VGPR,
// no spill) + R2's zero-VGPR async staging: 8x global_load_lds_dwordx4/wave
// for batch b+1 issued at top of b's compute, drained vmcnt(0)+barrier at
// iteration end. LDS swizzle preserved via inverse-swizzled per-lane GLOBAL
// source (linear LDS dest). LDS 66.8 KB -> 2 blocks/CU. NATURAL allocation:
// R1/R2 proved demand >~128 VGPR spills catastrophically and hints don't
// raise the cap -- payload must be zero-register, which gll provides.
// ---------------------------------------------------------------------------
__global__ __launch_bounds__(256) void attn_kernel(
    const ushort* __restrict__ fbf, const ushort* __restrict__ W1p,
    const float* __restrict__ V, const float* __restrict__ bV,
    const ushort* __restrict__ ph, float* __restrict__ out)
{
    __shared__ ushort As[2][64 * 256];   // 2 x 32 KB, chunk (m,c) at m*32 + (c^(m&31))
    __shared__ float lpart[4][64];
    __shared__ float wls[64];

    const int t    = threadIdx.x;
    const int w    = t >> 6;
    const int lane = t & 63;
    const int ml   = lane & 15;
    const int q    = lane >> 4;
    const int b0   = blockIdx.x * NB;

    // issue one 64x256 bf16 tile (32 KB) async: 8 instrs/wave, 1 KB each.
    // LDS chunk p = m*32+cc receives global chunk m*32 + (cc ^ (m&31)).
#define ISSUE(bb, buf) do {                                                   \
        const ushort* fb_ = fbf + (size_t)(bb) * (L_N * D_N);                 \
        _Pragma("unroll")                                                     \
        for (int i = 0; i < 8; ++i) {                                         \
            int p0_ = w * 512 + i * 64;          /* wave-uniform */           \
            int p_  = p0_ + lane;                                             \
            int m_  = p_ >> 5, cc_ = p_ & 31;                                 \
            int s_  = m_ * 32 + (cc_ ^ (m_ & 31));                            \
            gll16(fb_ + (size_t)s_ * 8, &As[buf][p0_ * 8]);                   \
        }                                                                     \
    } while (0)

    // prologue: stage b0 into buffer 0
    ISSUE(b0, 0);
    asm volatile("s_waitcnt vmcnt(0)" ::: "memory");
    __syncthreads();

    const ushort* W1w = W1p + (size_t)(w * 8) * 8 * 64 * 8;  // wave's 128-u strip
    int cur = 0;

    for (int bi = 0; bi < NB; ++bi) {
        const int b = b0 + bi;

        // async-issue next tile into the free buffer; drains under this
        // iteration's MFMA + epilogue
        if (bi + 1 < NB) ISSUE(b + 1, cur ^ 1);
        __builtin_amdgcn_sched_barrier(0);

        float lp[16];
#pragma unroll
        for (int j = 0; j < 16; ++j) lp[j] = 0.f;

        for (int uc = 0; uc < 4; ++uc) {
            f32x4 acc[4][2];
#pragma unroll
            for (int mt = 0; mt < 4; ++mt)
#pragma unroll
                for (int nt = 0; nt < 2; ++nt)
                    acc[mt][nt] = (f32x4){0.f, 0.f, 0.f, 0.f};

            // B-frag double buffer: load ks=0 pair up front
            bf16x8 bfc[2], bfn[2];
#pragma unroll
            for (int nt = 0; nt < 2; ++nt)
                bfc[nt] = *(const bf16x8*)&W1w[(size_t)(((uc * 2 + nt) * 8 + 0) * 64 + lane) * 8];

            for (int ks = 0; ks < 8; ++ks) {
                if (ks < 7) {
#pragma unroll
                    for (int nt = 0; nt < 2; ++nt)
                        bfn[nt] = *(const bf16x8*)&W1w[(size_t)(((uc * 2 + nt) * 8 + ks + 1) * 64 + lane) * 8];
                }
                bf16x8 a[4];
#pragma unroll
                for (int mt = 0; mt < 4; ++mt) {
                    int m = mt * 16 + ml;
                    int c = ks * 4 + q;
                    a[mt] = *(const bf16x8*)&As[cur][(m * 32 + (c ^ (m & 31))) * 8];
                }
#pragma unroll
                for (int nt = 0; nt < 2; ++nt)
#pragma unroll
                    for (int mt = 0; mt < 4; ++mt)
                        acc[mt][nt] = __builtin_amdgcn_mfma_f32_16x16x32_bf16(
                            a[mt], bfc[nt], acc[mt][nt], 0, 0, 0);
                bfc[0] = bfn[0]; bfc[1] = bfn[1];
            }

            // fold this 32-u chunk into persistent lp.  D: n=nt*16+ml, m=mt*16+q*4+r
#pragma unroll
            for (int nt = 0; nt < 2; ++nt) {
                int n = w * 128 + uc * 32 + nt * 16 + ml;
                float phv = bf2f(ph[(size_t)b * U_N + n]);
                float vv  = V[n];
#pragma unroll
                for (int mt = 0; mt < 4; ++mt)
#pragma unroll
                    for (int r = 0; r < 4; ++r) {
                        float s = fast_tanh(acc[mt][nt][r] + phv);
                        lp[mt * 4 + r] = fmaf(s, vv, lp[mt * 4 + r]);
                    }
            }
        }

        // one shuffle-reduce over the 16 n-lanes (xor 1,2,4,8 stays within q-group)
#pragma unroll
        for (int off = 1; off <= 8; off <<= 1)
#pragma unroll
            for (int j = 0; j < 16; ++j)
                lp[j] += __shfl_xor(lp[j], off);

        if (ml == 0) {
#pragma unroll
            for (int mt = 0; mt < 4; ++mt)
#pragma unroll
                for (int r = 0; r < 4; ++r)
                    lpart[w][mt * 16 + q * 4 + r] = lp[mt * 4 + r];
        }
        __syncthreads();   // BARRIER B: lpart ready

        if (t < 64) {
            float lsum = bV[0] + lpart[0][t] + lpart[1][t] + lpart[2][t] + lpart[3][t];
            float mx = lsum;
#pragma unroll
            for (int off = 32; off > 0; off >>= 1)
                mx = fmaxf(mx, __shfl_xor(mx, off));
            float e = __expf(lsum - mx);
            float ssum = e;
#pragma unroll
            for (int off = 32; off > 0; off >>= 1)
                ssum += __shfl_xor(ssum, off);
            float wt = e / ssum;
            wls[t] = wt;
            out[(size_t)B_N * D_N + (size_t)b * L_N + t] = wt;
        }
        __syncthreads();   // BARRIER C: wls ready

        // context[d] = sum_l w_l * f[l][d], from LDS bf16 (t == d)
        float ctx = 0.f;
#pragma unroll 16
        for (int l = 0; l < L_N; ++l) {
            ushort u = As[cur][(l * 32 + ((t >> 3) ^ (l & 31))) * 8 + (t & 7)];
            ctx = fmaf(wls[l], bf2f(u), ctx);
        }
        out[(size_t)b * D_N + t] = ctx;

        // drain our async loads (As[cur^1]) + cross-wave visibility; also
        // closes this iteration's ctx reads of As[cur] before next overwrite.
        asm volatile("s_waitcnt vmcnt(0)" ::: "memory");
        __syncthreads();
        cur ^= 1;
    }
#undef ISSUE
}

// ---------------------------------------------------------------------------
extern "C" void kernel_launch(void* const* d_in, const int* in_sizes, int n_in,
                              void* d_out, int out_size, void* d_ws, size_t ws_size,
                              hipStream_t stream) {
    const float* features = (const float*)d_in[0];
    const float* hidden   = (const float*)d_in[1];
    const float* W1       = (const float*)d_in[2];
    const float* b1       = (const float*)d_in[3];
    const float* W2       = (const float*)d_in[4];
    const float* b2       = (const float*)d_in[5];
    const float* V        = (const float*)d_in[6];
    const float* bV       = (const float*)d_in[7];
    float* out = (float*)d_out;

    // ws: ph bf16 2 MB | W1p 256 KB | W2p 512 KB | fbf bf16 64 MB
    ushort* ph  = (ushort*)d_ws;
    ushort* W1p = (ushort*)((char*)d_ws + (size_t)B_N * U_N * 2);
    ushort* W2p = (ushort*)((char*)d_ws + (size_t)B_N * U_N * 2 + (size_t)D_N * U_N * 2);
    ushort* fbf = (ushort*)((char*)d_ws + (size_t)B_N * U_N * 2 + (size_t)D_N * U_N * 2
                                        + (size_t)U_N * U_N * 2);

    pack_weights<<<192, 256, 0, stream>>>(W1, W2, W1p, W2p);
    proj_conv<<<512 + B_N, 256, 0, stream>>>(hidden, W2p, b1, b2, features, ph, fbf);
    attn_kernel<<<B_N / NB, 256, 0, stream>>>(fbf, W1p, V, bV, ph, out);
}